// Round 9
// baseline (218.278 us; speedup 1.0000x reference)
//
#include <hip/hip_runtime.h>

#define TOKENS 16384
#define DIM    256
#define NEMB   1024
#define KB2    512     // bf16 K per matrix row: [hi chunks 0-3 | lo chunks 4-7] x 64
#define BM     128     // token tile
#define BN     128     // embed tile
#define NSTEP  12      // 3-term split GEMM: s0-3 Ah*Bh, s4-7 Ah*Bl, s8-11 Al*Bh
#define GAPTHR 0.01f   // > 2*split-err(~2e-3) + pack quantum(~2e-3)

typedef __attribute__((ext_vector_type(8))) short short8;
typedef __attribute__((ext_vector_type(4))) float f32x4;

__device__ __forceinline__ unsigned fsort(float f) {   // monotone float->u32
    unsigned u = __float_as_uint(f);
    return (u & 0x80000000u) ? ~u : (u | 0x80000000u);
}
__device__ __forceinline__ float funsort(unsigned s) { // inverse of fsort
    unsigned u = (s & 0x80000000u) ? (s & 0x7FFFFFFFu) : ~s;
    return __uint_as_float(u);
}
__device__ __forceinline__ unsigned short bf16_rn(float f) {
    unsigned u = __float_as_uint(f);
    u += 0x7fff + ((u >> 16) & 1);
    return (unsigned short)(u >> 16);
}
__device__ __forceinline__ float bf16_to_f(unsigned short h) {
    return __uint_as_float((unsigned)h << 16);
}

// state[token] = (s1_ceil:27 | s2_floor:27 | n1:10).  s1 rounded UP, s2 rounded
// DOWN -> gap estimate is a lower bound; rounding ties auto-fail certification.
__device__ __forceinline__ void upd_state(unsigned long long* p,
                                          unsigned w1, unsigned w2, unsigned wn) {
    unsigned long long cur = *p;
    while (true) {
        const unsigned a1 = (unsigned)(cur >> 37);
        const unsigned a2 = (unsigned)((cur >> 10) & 0x7FFFFFFu);
        const unsigned an = (unsigned)(cur & 1023u);
        unsigned s1, s2, n1;
        if (w1 > a1)      { s1 = a1; n1 = an; s2 = min(a2, w1 - 1); }
        else if (w1 < a1) { s1 = w1; n1 = wn; s2 = min(w2, a1 - 1); }
        else              { s1 = a1; n1 = min(an, wn); s2 = min(min(a2, w2), a1 - 1); }
        const unsigned long long des =
            ((unsigned long long)s1 << 37) | ((unsigned long long)s2 << 10) | n1;
        if (des == cur) return;
        const unsigned long long old = atomicCAS(p, cur, des);
        if (old == cur) return;
        cur = old;
    }
}

// ------- prep: split x,E into bf16 hi/lo; exact fp32 esq; init state -------
__global__ __launch_bounds__(256) void prep_kernel(const float* __restrict__ x,
                                                   const float* __restrict__ E,
                                                   unsigned short* __restrict__ xbf,
                                                   unsigned short* __restrict__ ebf,
                                                   float* __restrict__ esq,
                                                   unsigned long long* __restrict__ state) {
    const int tid = blockIdx.x * 256 + threadIdx.x;
    if (tid < TOKENS) state[tid] = ~0ull;   // (+inf, +inf, n=1023); ws is re-poisoned
    const int wave = tid >> 6;
    const int lane = threadIdx.x & 63;
    #pragma unroll 1
    for (int rr = 0; rr < 4; ++rr) {
        const int row = wave * 4 + rr;                       // 0..17407, wave-uniform
        const bool isE = row >= TOKENS;
        const float* src = isE ? (E + (size_t)(row - TOKENS) * DIM)
                               : (x + (size_t)row * DIM);
        const float4 v = reinterpret_cast<const float4*>(src)[lane];
        const float f[4] = {v.x, v.y, v.z, v.w};
        unsigned long long hv = 0, lv = 0;
        #pragma unroll
        for (int i = 0; i < 4; ++i) {
            const unsigned short h = bf16_rn(f[i]);
            const float r = f[i] - bf16_to_f(h);             // exact (Sterbenz)
            const unsigned short l = bf16_rn(r);
            hv |= (unsigned long long)h << (16 * i);
            lv |= (unsigned long long)l << (16 * i);
        }
        unsigned short* dst = isE ? (ebf + (size_t)(row - TOKENS) * KB2)
                                  : (xbf + (size_t)row * KB2);
        *reinterpret_cast<unsigned long long*>(dst + 4 * lane)       = hv;
        *reinterpret_cast<unsigned long long*>(dst + 256 + 4 * lane) = lv;
        if (isE) {
            float s = fmaf(v.x, v.x, fmaf(v.y, v.y, fmaf(v.z, v.z, v.w * v.w)));
            #pragma unroll
            for (int off = 32; off > 0; off >>= 1) s += __shfl_down(s, off);
            if (lane == 0) esq[row - TOKENS] = s;
        }
    }
}

#define WAITV8 do { asm volatile("s_waitcnt vmcnt(8)" ::: "memory"); \
                    __builtin_amdgcn_sched_barrier(0); } while (0)
#define WAITV0 do { asm volatile("s_waitcnt vmcnt(0)" ::: "memory"); \
                    __builtin_amdgcn_sched_barrier(0); } while (0)
#define BAR()  do { __builtin_amdgcn_s_barrier(); \
                    __builtin_amdgcn_sched_barrier(0); } while (0)

// ------- 3-term split GEMM: R4 2-phase dbuf + T4 counted vmcnt -------
// grid 1024 XCD-swizzled; 4 waves (2x2), wave tile 64x64 = 4x4 frags 16x16x32.
__global__ __launch_bounds__(256) void vq_mfma(const unsigned short* __restrict__ xbf,
                                               const unsigned short* __restrict__ ebf,
                                               const float* __restrict__ esq,
                                               unsigned long long* __restrict__ state) {
    __shared__ unsigned short ls[2][(BM + BN) * 64];   // 2 x 32KB double buffer

    const int t    = threadIdx.x;
    const int lane = t & 63;
    const int w    = t >> 6;             // wave 0..3
    const int wr   = w >> 1, wc = w & 1;
    const int bid  = (int)blockIdx.x;    // T1 XCD swizzle (1024 % 8 == 0, bijective)
    const int lb   = (bid & 7) * 128 + (bid >> 3);
    const int m0   = (lb & 127) * BM;
    const int n0   = (lb >> 7) * BN;

    f32x4 acc[4][4];
    #pragma unroll
    for (int i = 0; i < 4; ++i)
        #pragma unroll
        for (int j = 0; j < 4; ++j) acc[i][j] = (f32x4){0.f, 0.f, 0.f, 0.f};

    const int srow   = lane >> 3;                 // row within 8-row staging group
    const int schunk = (lane & 7) ^ srow;         // pre-swizzled 16B chunk of the 128B row

    // stage K-step s (8 global_load_lds per wave; chunks 0-3 = hi, 4-7 = lo)
    auto stage = [&](char* lbase, int s) {
        const int ksA = (s < 4) ? s : (s - 4);    // A: hi(0-3), hi(0-3), lo(4-7)
        const int ksB = (s < 8) ? s : (s - 8);    // B: hi(0-3), lo(4-7), hi(0-3)
        #pragma unroll
        for (int c = 0; c < 4; ++c) {
            const int ra = m0 + w * 32 + c * 8 + srow;
            const int rb = n0 + w * 32 + c * 8 + srow;
            const char* ga = (const char*)(xbf + (size_t)ra * KB2 + ksA * 64) + schunk * 16;
            const char* gb = (const char*)(ebf + (size_t)rb * KB2 + ksB * 64) + schunk * 16;
            __builtin_amdgcn_global_load_lds(
                (const __attribute__((address_space(1))) unsigned int*)ga,
                (__attribute__((address_space(3))) unsigned int*)(lbase + (w * 32 + c * 8) * 128),
                16, 0, 0);
            __builtin_amdgcn_global_load_lds(
                (const __attribute__((address_space(1))) unsigned int*)gb,
                (__attribute__((address_space(3))) unsigned int*)(lbase + (BM + w * 32 + c * 8) * 128),
                16, 0, 0);
        }
    };

    auto compute = [&](const char* lbase) {
        const int rA = lane & 15;
        const int g  = lane >> 4;
        #pragma unroll
        for (int kh = 0; kh < 2; ++kh) {
            short8 af[4], bfr[4];
            #pragma unroll
            for (int mf = 0; mf < 4; ++mf) {
                const int row = wr * 64 + mf * 16 + rA;
                const int ch  = (kh * 4 + g) ^ (row & 7);    // read-side un-swizzle
                af[mf] = *(const short8*)(lbase + row * 128 + ch * 16);
            }
            #pragma unroll
            for (int nf = 0; nf < 4; ++nf) {
                const int row = wc * 64 + nf * 16 + rA;
                const int ch  = (kh * 4 + g) ^ (row & 7);
                bfr[nf] = *(const short8*)(lbase + (BM + row) * 128 + ch * 16);
            }
            #pragma unroll
            for (int mf = 0; mf < 4; ++mf)
                #pragma unroll
                for (int nf = 0; nf < 4; ++nf)
                    acc[mf][nf] = __builtin_amdgcn_mfma_f32_16x16x32_bf16(
                        af[mf], bfr[nf], acc[mf][nf], 0, 0, 0);
        }
    };

    char* const b0 = (char*)ls[0];
    char* const b1 = (char*)ls[1];

    // Counted-vmcnt pipeline: tile t+1's loads stay in flight across the
    // read-barrier; vmcnt never drains to 0 until the tail.
    stage(b0, 0);
    stage(b1, 1);                 // 16 outstanding
    WAITV8; BAR();                // oldest 8 (tile 0) landed -> b0 ready
    #pragma unroll 1
    for (int sp = 0; sp < NSTEP; ++sp) {
        char* const cb = (sp & 1) ? b1 : b0;
        compute(cb);              // tile sp
        if (sp == NSTEP - 1) break;
        BAR();                    // all waves done READING cb (no vmcnt drain)
        if (sp + 2 < NSTEP) { stage(cb, sp + 2); WAITV8; }   // wait tile sp+1 only
        else                { WAITV0; }                      // tail: drain last tile
        BAR();                    // tile sp+1 published
    }

    // epilogue: d2 = esq[n] - 2*dot; per-row (min1, idx1, min2) -> CAS state
    const int g  = lane >> 4;    // C/D: col = lane&15, row = g*4 + reg
    const int cl = lane & 15;
    float eq[4];
    #pragma unroll
    for (int nf = 0; nf < 4; ++nf) eq[nf] = esq[n0 + wc * 64 + nf * 16 + cl];

    #pragma unroll
    for (int mf = 0; mf < 4; ++mf)
        #pragma unroll
        for (int j = 0; j < 4; ++j) {
            float v1 = 3.4e38f, v2 = 3.4e38f;
            int   i1 = 0;
            #pragma unroll
            for (int nf = 0; nf < 4; ++nf) {      // ascending n within lane
                const int   n = n0 + wc * 64 + nf * 16 + cl;
                const float d = fmaf(-2.f, acc[mf][nf][j], eq[nf]);
                if (d < v1) { v2 = v1; v1 = d; i1 = n; }
                else        { v2 = fminf(v2, d); }
            }
            #pragma unroll
            for (int off = 8; off >= 1; off >>= 1) {    // 16-lane sorted-pair merge
                const float o1 = __shfl_xor(v1, off);
                const int   oi = __shfl_xor(i1, off);
                const float o2 = __shfl_xor(v2, off);
                const float n2 = fminf(fminf(v2, o2), fmaxf(v1, o1));
                if (o1 < v1 || (o1 == v1 && oi < i1)) { v1 = o1; i1 = oi; }
                v2 = n2;
            }
            if (cl == 0) {
                const int row = m0 + wr * 64 + mf * 16 + g * 4 + j;
                const unsigned c1 = (unsigned)(((unsigned long long)fsort(v1) + 31) >> 5); // ceil
                const unsigned c2 = fsort(v2) >> 5;                                        // floor
                upd_state(&state[row], c1, c2, (unsigned)i1);
            }
        }
}

// ------- finish: certified -> gather E[n1]; near-ties -> block-local exact f64 -------
__global__ __launch_bounds__(256) void vq_finish(const float* __restrict__ x,
                                                 const float* __restrict__ E,
                                                 const unsigned long long* __restrict__ state,
                                                 float* __restrict__ out) {
    __shared__ int    pend[16];
    __shared__ int    npend;
    __shared__ float  xs[DIM];
    __shared__ double wd[4];
    __shared__ int    wi[4];
    if (threadIdx.x == 0) npend = 0;
    __syncthreads();

    const int w    = threadIdx.x >> 6;
    const int lane = threadIdx.x & 63;
    #pragma unroll 1
    for (int i = 0; i < 4; ++i) {
        const int tok = blockIdx.x * 16 + w * 4 + i;
        const unsigned long long st = state[tok];
        const unsigned a1 = (unsigned)(st >> 37);
        const unsigned a2 = (unsigned)((st >> 10) & 0x7FFFFFFu);
        const int      n1 = (int)(st & 1023u);
        const float d1ub = funsort(a1 << 5);     // >= true min1
        const float d2lb = funsort(a2 << 5);     // <= true min2
        if (d2lb - d1ub > GAPTHR) {
            const float4 ev = reinterpret_cast<const float4*>(E + (size_t)n1 * DIM)[lane];
            reinterpret_cast<float4*>(out + (size_t)tok * DIM)[lane] = ev;
        } else if (lane == 0) {
            pend[atomicAdd(&npend, 1)] = tok;    // shared-mem atomic, <=16
        }
    }
    __syncthreads();

    const int np = npend;
    #pragma unroll 1
    for (int p = 0; p < np; ++p) {               // rare: exact block-parallel re-rank
        const int tok = pend[p];
        __syncthreads();
        xs[threadIdx.x] = x[(size_t)tok * DIM + threadIdx.x];
        __syncthreads();
        double bd = 1e300;
        int    bn = 0;
        #pragma unroll 1
        for (int cgrp = 0; cgrp < 4; ++cgrp) {   // thread owns 4 codes
            const int n = cgrp * 256 + threadIdx.x;
            const float* er = E + (size_t)n * DIM;
            double s = 0.0;
            #pragma unroll 4
            for (int k = 0; k < DIM; k += 4) {
                const float4 ev = *(const float4*)(er + k);
                const double d0 = (double)xs[k + 0] - (double)ev.x;
                const double d1 = (double)xs[k + 1] - (double)ev.y;
                const double d2 = (double)xs[k + 2] - (double)ev.z;
                const double d3 = (double)xs[k + 3] - (double)ev.w;
                s += d0 * d0 + d1 * d1 + d2 * d2 + d3 * d3;
            }
            if (s < bd || (s == bd && n < bn)) { bd = s; bn = n; }  // lowest-idx ties
        }
        #pragma unroll
        for (int off = 32; off > 0; off >>= 1) {
            const double od = __shfl_down(bd, off);
            const int    on = __shfl_down(bn, off);
            if (od < bd || (od == bd && on < bn)) { bd = od; bn = on; }
        }
        if (lane == 0) { wd[w] = bd; wi[w] = bn; }
        __syncthreads();
        double b = wd[0]; int best = wi[0];
        #pragma unroll
        for (int i = 1; i < 4; ++i)
            if (wd[i] < b || (wd[i] == b && wi[i] < best)) { b = wd[i]; best = wi[i]; }
        out[(size_t)tok * DIM + threadIdx.x] = E[(size_t)best * DIM + threadIdx.x];
    }
}

extern "C" void kernel_launch(void* const* d_in, const int* in_sizes, int n_in,
                              void* d_out, int out_size, void* d_ws, size_t ws_size,
                              hipStream_t stream) {
    const float* x = (const float*)d_in[0];    // [16,1024,256] fp32
    const float* E = (const float*)d_in[1];    // [1024,256] fp32
    float* out = (float*)d_out;

    // ws: state 128KB | esq 4KB | ebf 1MB  (~1.16MB)
    unsigned long long* state = (unsigned long long*)d_ws;
    float* esq          = (float*)((char*)d_ws + 131072);
    unsigned short* ebf = (unsigned short*)((char*)d_ws + 131072 + 4096);
    // x split lives in d_out (16384*512*2B == out bytes exactly); fully consumed
    // by vq_mfma before vq_finish overwrites d_out with the result.
    unsigned short* xbf = (unsigned short*)d_out;

    prep_kernel<<<(TOKENS + NEMB) / 16, 256, 0, stream>>>(x, E, xbf, ebf, esq, state);
    vq_mfma<<<1024, 256, 0, stream>>>(xbf, ebf, esq, state);
    vq_finish<<<TOKENS / 16, 256, 0, stream>>>(x, E, state, out);
}